// Round 1
// baseline (4328.479 us; speedup 1.0000x reference)
//
#include <hip/hip_runtime.h>
#include <stdint.h>

#define T_SEQ 512
#define BATCH 256
#define HID   128
#define G4    512   // 4*H
#define XD    257
#define ZD    16

// ---------- helpers ----------
__device__ __forceinline__ float bf2f(uint16_t u) {
  union { uint32_t i; float f; } v; v.i = ((uint32_t)u) << 16; return v.f;
}
__device__ __forceinline__ uint16_t f2bf(float f) {
  union { float f; uint32_t i; } v; v.f = f;
  uint32_t r = v.i + 0x7fffu + ((v.i >> 16) & 1u);
  return (uint16_t)(r >> 16);
}
__device__ __forceinline__ float sigf(float x) { return 1.0f / (1.0f + __expf(-x)); }
__device__ __forceinline__ float tanhfast(float x) { return 2.0f / (1.0f + __expf(-2.0f * x)) - 1.0f; }

// ---------- kernel 1: weight transposes ----------
__global__ void k_prep(const float* __restrict__ Wih_gx, const float* __restrict__ Wy,
                       float* __restrict__ wT, float* __restrict__ wyT) {
  int idx = blockIdx.x * 256 + threadIdx.x;
  const int N1 = XD * G4;          // 131584
  const int N2 = HID * XD;         // 32896
  if (idx < N1) {
    int j = idx & (G4 - 1), d = idx >> 9;       // wT[d*512+j] = Wih_gx[j*257+d]
    wT[idx] = Wih_gx[j * XD + d];
  } else if (idx < N1 + N2) {
    int i2 = idx - N1;
    int u = i2 / XD, d = i2 % XD;               // wyT[u*257+d] = Wy[d*128+u]
    wyT[i2] = Wy[d * HID + u];
  }
}

// ---------- kernel 2: px[t][b][j] = b_ih+b_hh + sum_d x[b][d][t]*Wih_gx[j][d] (bf16 out) ----------
__global__ __launch_bounds__(256) void k_proj(
    const float* __restrict__ x, const float* __restrict__ wT,
    const float* __restrict__ bih, const float* __restrict__ bhh,
    uint16_t* __restrict__ px) {
  __shared__ uint16_t xs[XD * 66];
  int tid = threadIdx.x;
  int t0 = blockIdx.x * 64, b = blockIdx.y;
  int lane = tid & 63;
  {
    int t = tid & 63, d0 = tid >> 6;
    for (int d = d0; d < XD; d += 4)
      xs[d * 66 + t] = f2bf(x[((size_t)b * XD + d) * T_SEQ + t0 + t]);
  }
  __syncthreads();
  int w = __builtin_amdgcn_readfirstlane(tid >> 6);
  for (int p = 0; p < 8; ++p) {
    int j0 = w * 128 + p * 16;
    float acc[16];
#pragma unroll
    for (int i = 0; i < 16; ++i) acc[i] = bih[j0 + i] + bhh[j0 + i];
    for (int d = 0; d < XD; ++d) {
      float xv = bf2f(xs[d * 66 + lane]);
      const float* wrow = wT + (size_t)d * G4 + j0;
#pragma unroll
      for (int i = 0; i < 16; ++i) acc[i] = fmaf(wrow[i], xv, acc[i]);
    }
    size_t base = ((size_t)(t0 + lane) * BATCH + b) * G4 + j0;
    uint32_t pk[8];
#pragma unroll
    for (int i = 0; i < 8; ++i)
      pk[i] = (uint32_t)f2bf(acc[2 * i]) | ((uint32_t)f2bf(acc[2 * i + 1]) << 16);
    uint4* dst = (uint4*)(px + base);
    dst[0] = make_uint4(pk[0], pk[1], pk[2], pk[3]);
    dst[1] = make_uint4(pk[4], pk[5], pk[6], pk[7]);
  }
}

// ---------- kernel 3: backward LSTM g_x (1 WG per batch row; Whh row in VGPRs) ----------
__global__ __launch_bounds__(512, 2) void k_lstm_gx(
    const uint16_t* __restrict__ px, const float* __restrict__ Whh,
    uint16_t* __restrict__ gx) {
  __shared__ __align__(16) float hl[HID];
  __shared__ float gact[G4];
  int j = threadIdx.x, b = blockIdx.x;
  float wr[HID];
#pragma unroll
  for (int k = 0; k < HID; ++k) wr[k] = Whh[(size_t)j * HID + k];
  if (j < HID) hl[j] = 0.0f;
  float c = 0.0f;
  int jb = j >> 7;  // 0:i 1:f 2:g 3:o
  uint16_t pcur = px[((size_t)(T_SEQ - 1) * BATCH + b) * G4 + j];
  __syncthreads();
  for (int t = T_SEQ - 1; t >= 0; --t) {
    int tn = t > 0 ? t - 1 : 0;
    uint16_t pnext = px[((size_t)tn * BATCH + b) * G4 + j];
    float pre = bf2f(pcur);
    const float4* h4 = (const float4*)hl;
#pragma unroll
    for (int k4 = 0; k4 < HID / 4; ++k4) {
      float4 h = h4[k4];
      pre = fmaf(wr[4 * k4 + 0], h.x, pre);
      pre = fmaf(wr[4 * k4 + 1], h.y, pre);
      pre = fmaf(wr[4 * k4 + 2], h.z, pre);
      pre = fmaf(wr[4 * k4 + 3], h.w, pre);
    }
    gact[j] = (jb == 2) ? tanhfast(pre) : sigf(pre);
    __syncthreads();
    if (j < HID) {
      float gi = gact[j], gf = gact[j + HID], gg = gact[j + 2 * HID], go = gact[j + 3 * HID];
      c = gf * c + gi * gg;
      float h = go * tanhfast(c);
      hl[j] = h;
      gx[((size_t)t * BATCH + b) * HID + j] = f2bf(h);
    }
    pcur = pnext;
    __syncthreads();
  }
}

// ---------- kernel 4: fused inference (h/mean/logvar/z + g_z LSTM cell) ----------
__global__ __launch_bounds__(512, 2) void k_inf(
    const uint16_t* __restrict__ gx, const float* __restrict__ eps,
    const float* __restrict__ Wih_gz, const float* __restrict__ Whh_gz,
    const float* __restrict__ bih_gz, const float* __restrict__ bhh_gz,
    const float* __restrict__ W0, const float* __restrict__ b0,
    const float* __restrict__ Wm, const float* __restrict__ bm,
    const float* __restrict__ Wv, const float* __restrict__ bv,
    float* __restrict__ zbuf, float* __restrict__ out_mean,
    float* __restrict__ out_logvar, float* __restrict__ out_z) {
  __shared__ __align__(16) float wgzT[ZD * G4];    // 32 KB, [k][j]
  __shared__ __align__(16) float wmvl[32 * HID];   // 16 KB, rows 0-15 Wm, 16-31 Wv
  __shared__ __align__(16) float gxl[HID];
  __shared__ __align__(16) float gzl[HID];
  __shared__ __align__(16) float hvec[HID];
  __shared__ __align__(16) float zl[ZD];
  __shared__ float gact[G4];
  __shared__ float mlv[32];
  __shared__ float bmvl[32];
  int tid = threadIdx.x, b = blockIdx.x;
  for (int idx = tid; idx < ZD * G4; idx += 512) {
    int jj = idx >> 4, kk = idx & 15;
    wgzT[kk * G4 + jj] = Wih_gz[idx];
  }
  for (int idx = tid; idx < 2 * ZD * HID; idx += 512)
    wmvl[idx] = (idx < ZD * HID) ? Wm[idx] : Wv[idx - ZD * HID];
  if (tid < 32) bmvl[tid] = (tid < 16) ? bm[tid] : bv[tid - 16];
  if (tid < HID) gzl[tid] = 0.0f;
  float wzr[HID];
#pragma unroll
  for (int k = 0; k < HID; ++k) wzr[k] = Whh_gz[(size_t)tid * HID + k];
  float bzr = bih_gz[tid] + bhh_gz[tid];
  int u = tid >> 2, s4 = tid & 3;
  float w0r[64];
#pragma unroll
  for (int i = 0; i < 64; ++i) w0r[i] = W0[(size_t)u * 256 + s4 * 64 + i];
  float b0r = b0[u];
  int o = tid >> 4, s16 = tid & 15;
  float czr = 0.0f;
  int jb = tid >> 7;
  float gxcur = (tid < HID) ? bf2f(gx[((size_t)0 * BATCH + b) * HID + tid]) : 0.0f;
  float epcur = (tid < ZD) ? eps[((size_t)0 * BATCH + b) * ZD + tid] : 0.0f;
  __syncthreads();
  for (int t = 0; t < T_SEQ; ++t) {
    int tn = (t < T_SEQ - 1) ? t + 1 : t;
    if (tid < HID) gxl[tid] = gxcur;
    float gxnext = (tid < HID) ? bf2f(gx[((size_t)tn * BATCH + b) * HID + tid]) : 0.0f;
    float epnext = (tid < ZD) ? eps[((size_t)tn * BATCH + b) * ZD + tid] : 0.0f;
    __syncthreads();
    // h = tanh([gx, gz] @ W0.T + b0): 4 lanes per u, shuffle-reduce
    {
      const float4* src = (const float4*)((s4 < 2) ? (gxl + s4 * 64) : (gzl + (s4 - 2) * 64));
      float p = 0.0f;
#pragma unroll
      for (int i4 = 0; i4 < 16; ++i4) {
        float4 v = src[i4];
        p = fmaf(w0r[4 * i4 + 0], v.x, p);
        p = fmaf(w0r[4 * i4 + 1], v.y, p);
        p = fmaf(w0r[4 * i4 + 2], v.z, p);
        p = fmaf(w0r[4 * i4 + 3], v.w, p);
      }
      p += __shfl_xor(p, 1);
      p += __shfl_xor(p, 2);
      if (s4 == 0) hvec[u] = tanhfast(p + b0r);
    }
    __syncthreads();
    // mean/logvar: 16 lanes per output o, shuffle-reduce
    {
      const float4* hh = (const float4*)(hvec + s16 * 8);
      const float4* wm4 = (const float4*)(wmvl + o * HID + s16 * 8);
      float4 h0 = hh[0], h1 = hh[1], m0 = wm4[0], m1 = wm4[1];
      float p = h0.x * m0.x + h0.y * m0.y + h0.z * m0.z + h0.w * m0.w +
                h1.x * m1.x + h1.y * m1.y + h1.z * m1.z + h1.w * m1.w;
      p += __shfl_xor(p, 1);
      p += __shfl_xor(p, 2);
      p += __shfl_xor(p, 4);
      p += __shfl_xor(p, 8);
      if (s16 == 0) {
        float v = p + bmvl[o];
        mlv[o] = v;
        if (o < 16) out_mean[((size_t)b * ZD + o) * T_SEQ + t] = v;
        else        out_logvar[((size_t)b * ZD + (o - 16)) * T_SEQ + t] = v;
      }
    }
    __syncthreads();
    if (tid < ZD) {
      float zv = epcur * __expf(0.5f * mlv[16 + tid]) + mlv[tid];
      zl[tid] = zv;
      zbuf[((size_t)t * BATCH + b) * ZD + tid] = zv;
      out_z[((size_t)b * ZD + tid) * T_SEQ + t] = zv;
    }
    __syncthreads();
    // g_z LSTM cell gates (uses OLD gzl, matching the reference carry)
    {
      float pre = bzr;
#pragma unroll
      for (int k = 0; k < ZD; ++k) pre = fmaf(zl[k], wgzT[k * G4 + tid], pre);
      const float4* g4 = (const float4*)gzl;
#pragma unroll
      for (int k4 = 0; k4 < HID / 4; ++k4) {
        float4 g = g4[k4];
        pre = fmaf(wzr[4 * k4 + 0], g.x, pre);
        pre = fmaf(wzr[4 * k4 + 1], g.y, pre);
        pre = fmaf(wzr[4 * k4 + 2], g.z, pre);
        pre = fmaf(wzr[4 * k4 + 3], g.w, pre);
      }
      gact[tid] = (jb == 2) ? tanhfast(pre) : sigf(pre);
    }
    __syncthreads();
    if (tid < HID) {
      float gi = gact[tid], gf = gact[tid + HID], gg = gact[tid + 2 * HID], go = gact[tid + 3 * HID];
      czr = gf * czr + gi * gg;
      gzl[tid] = go * tanhfast(czr);
    }
    gxcur = gxnext;
    epcur = epnext;
    __syncthreads();
  }
}

// ---------- kernel 5: decoder LSTM over z ----------
__global__ __launch_bounds__(512, 2) void k_dec(
    const float* __restrict__ zbuf, const float* __restrict__ Wih_h,
    const float* __restrict__ Whh_h, const float* __restrict__ bih,
    const float* __restrict__ bhh, uint16_t* __restrict__ hdec) {
  __shared__ __align__(16) float wihT[ZD * G4];   // 32 KB [k][j]
  __shared__ __align__(16) float hl[HID];
  __shared__ float gact[G4];
  __shared__ float zlcur[ZD];
  int j = threadIdx.x, b = blockIdx.x;
  for (int idx = j; idx < ZD * G4; idx += 512) {
    int jj = idx >> 4, kk = idx & 15;
    wihT[kk * G4 + jj] = Wih_h[idx];
  }
  float wr[HID];
#pragma unroll
  for (int k = 0; k < HID; ++k) wr[k] = Whh_h[(size_t)j * HID + k];
  float bz = bih[j] + bhh[j];
  if (j < HID) hl[j] = 0.0f;
  float c = 0.0f;
  int jb = j >> 7;
  float zcur = (j < ZD) ? zbuf[((size_t)0 * BATCH + b) * ZD + j] : 0.0f;
  __syncthreads();
  for (int t = 0; t < T_SEQ; ++t) {
    if (j < ZD) zlcur[j] = zcur;
    int tn = (t < T_SEQ - 1) ? t + 1 : t;
    float znext = (j < ZD) ? zbuf[((size_t)tn * BATCH + b) * ZD + j] : 0.0f;
    __syncthreads();
    float pre = bz;
#pragma unroll
    for (int k = 0; k < ZD; ++k) pre = fmaf(zlcur[k], wihT[k * G4 + j], pre);
    const float4* h4 = (const float4*)hl;
#pragma unroll
    for (int k4 = 0; k4 < HID / 4; ++k4) {
      float4 h = h4[k4];
      pre = fmaf(wr[4 * k4 + 0], h.x, pre);
      pre = fmaf(wr[4 * k4 + 1], h.y, pre);
      pre = fmaf(wr[4 * k4 + 2], h.z, pre);
      pre = fmaf(wr[4 * k4 + 3], h.w, pre);
    }
    gact[j] = (jb == 2) ? tanhfast(pre) : sigf(pre);
    __syncthreads();
    if (j < HID) {
      float gi = gact[j], gf = gact[j + HID], gg = gact[j + 2 * HID], go = gact[j + 3 * HID];
      c = gf * c + gi * gg;
      float h = go * tanhfast(c);
      hl[j] = h;
      hdec[((size_t)t * BATCH + b) * HID + j] = f2bf(h);
    }
    zcur = znext;
    __syncthreads();
  }
}

// ---------- kernel 6: y = exp(hdec @ Wy.T + by), output (B, 257, T) ----------
__global__ __launch_bounds__(256) void k_y(
    const uint16_t* __restrict__ hdec, const float* __restrict__ wyT,
    const float* __restrict__ by, float* __restrict__ out_y) {
  __shared__ __align__(16) float hl[HID * 65];
  int tid = threadIdx.x;
  int t0 = blockIdx.x * 64, b = blockIdx.y;
  {
    int uu = tid & 127, tg = tid >> 7;
    for (int tt = tg; tt < 64; tt += 2)
      hl[uu * 65 + tt] = bf2f(hdec[((size_t)(t0 + tt) * BATCH + b) * HID + uu]);
  }
  __syncthreads();
  int w = __builtin_amdgcn_readfirstlane(tid >> 6);
  int lane = tid & 63;
  for (int p = 0; p < 4; ++p) {
    int d0 = w * 16 + p * 64;
    float acc[16];
#pragma unroll
    for (int i = 0; i < 16; ++i) acc[i] = by[d0 + i];
    for (int uu = 0; uu < HID; ++uu) {
      float hv = hl[uu * 65 + lane];
      const float* wrow = wyT + (size_t)uu * XD + d0;
#pragma unroll
      for (int i = 0; i < 16; ++i) acc[i] = fmaf(wrow[i], hv, acc[i]);
    }
#pragma unroll
    for (int i = 0; i < 16; ++i)
      out_y[((size_t)b * XD + d0 + i) * T_SEQ + t0 + lane] = __expf(acc[i]);
  }
  if (w == 0) {  // d = 256 tail
    float acc = by[256];
    for (int uu = 0; uu < HID; ++uu)
      acc = fmaf(wyT[(size_t)uu * XD + 256], hl[uu * 65 + lane], acc);
    out_y[((size_t)b * XD + 256) * T_SEQ + t0 + lane] = __expf(acc);
  }
}

extern "C" void kernel_launch(void* const* d_in, const int* in_sizes, int n_in,
                              void* d_out, int out_size, void* d_ws, size_t ws_size,
                              hipStream_t stream) {
  const float* x      = (const float*)d_in[0];
  const float* eps    = (const float*)d_in[1];
  const float* Wih_gx = (const float*)d_in[2];
  const float* Whh_gx = (const float*)d_in[3];
  const float* bih_gx = (const float*)d_in[4];
  const float* bhh_gx = (const float*)d_in[5];
  const float* Wih_gz = (const float*)d_in[6];
  const float* Whh_gz = (const float*)d_in[7];
  const float* bih_gz = (const float*)d_in[8];
  const float* bhh_gz = (const float*)d_in[9];
  const float* W0     = (const float*)d_in[10];
  const float* b0     = (const float*)d_in[11];
  const float* Wm     = (const float*)d_in[12];
  const float* bm     = (const float*)d_in[13];
  const float* Wv     = (const float*)d_in[14];
  const float* bv     = (const float*)d_in[15];
  const float* Wih_h  = (const float*)d_in[16];
  const float* Whh_h  = (const float*)d_in[17];
  const float* bih_h  = (const float*)d_in[18];
  const float* bhh_h  = (const float*)d_in[19];
  const float* Wy     = (const float*)d_in[20];
  const float* by     = (const float*)d_in[21];

  char* ws = (char*)d_ws;
  float*    wT   = (float*)(ws + 0);                       // 257*512 f32   = 526,336 B
  float*    wyT  = (float*)(ws + 526336);                  // 128*257 f32   = 131,584 B
  uint16_t* px   = (uint16_t*)(ws + (1u << 20));           // bf16 T*B*512  = 134,217,728 B
  uint16_t* gx   = (uint16_t*)(ws + 135266304);            // bf16 T*B*128  =  33,554,432 B
  float*    zbuf = (float*)(ws + 168820736);               // f32  T*B*16   =   8,388,608 B
  uint16_t* hdec = (uint16_t*)(ws + 177209344);            // bf16 T*B*128  =  33,554,432 B
  // total ws footprint = 210,763,776 B (~201 MB)

  float* out_y      = (float*)d_out;                         // (B,257,T)
  float* out_mean   = out_y + (size_t)BATCH * XD * T_SEQ;    // (B,16,T)
  float* out_logvar = out_mean + (size_t)BATCH * ZD * T_SEQ;
  float* out_z      = out_logvar + (size_t)BATCH * ZD * T_SEQ;

  k_prep<<<dim3(643), dim3(256), 0, stream>>>(Wih_gx, Wy, wT, wyT);
  k_proj<<<dim3(8, 256), dim3(256), 0, stream>>>(x, wT, bih_gx, bhh_gx, px);
  k_lstm_gx<<<dim3(256), dim3(512), 0, stream>>>(px, Whh_gx, gx);
  k_inf<<<dim3(256), dim3(512), 0, stream>>>(gx, eps, Wih_gz, Whh_gz, bih_gz, bhh_gz,
                                             W0, b0, Wm, bm, Wv, bv,
                                             zbuf, out_mean, out_logvar, out_z);
  k_dec<<<dim3(256), dim3(512), 0, stream>>>(zbuf, Wih_h, Whh_h, bih_h, bhh_h, hdec);
  k_y<<<dim3(8, 256), dim3(256), 0, stream>>>(hdec, wyT, by, out_y);
}

// Round 2
// 4276.726 us; speedup vs baseline: 1.0121x; 1.0121x over previous
//
#include <hip/hip_runtime.h>
#include <stdint.h>

#define T_SEQ 512
#define BATCH 256
#define HID   128
#define G4    512   // 4*H
#define XD    257
#define ZD    16

// ---------- helpers ----------
__device__ __forceinline__ float bf2f(uint16_t u) {
  union { uint32_t i; float f; } v; v.i = ((uint32_t)u) << 16; return v.f;
}
__device__ __forceinline__ uint16_t f2bf(float f) {
  union { float f; uint32_t i; } v; v.f = f;
  uint32_t r = v.i + 0x7fffu + ((v.i >> 16) & 1u);
  return (uint16_t)(r >> 16);
}
__device__ __forceinline__ float sigf(float x) { return 1.0f / (1.0f + __expf(-x)); }
__device__ __forceinline__ float tanhfast(float x) { return 2.0f / (1.0f + __expf(-2.0f * x)) - 1.0f; }
// unified gate activation: g==2 -> tanh, else sigmoid (no divergence)
__device__ __forceinline__ float gate_act(float pre, bool isg) {
  float s = isg ? (-2.0f * pre) : (-pre);
  float r = 1.0f / (1.0f + __expf(s));
  return isg ? (2.0f * r - 1.0f) : r;
}

// ---------- kernel 1: weight transposes ----------
__global__ void k_prep(const float* __restrict__ Wih_gx, const float* __restrict__ Wy,
                       float* __restrict__ wT, float* __restrict__ wyT) {
  int idx = blockIdx.x * 256 + threadIdx.x;
  const int N1 = XD * G4;          // 131584
  const int N2 = HID * XD;         // 32896
  if (idx < N1) {
    int j = idx & (G4 - 1), d = idx >> 9;       // wT[d*512+j] = Wih_gx[j*257+d]
    wT[idx] = Wih_gx[j * XD + d];
  } else if (idx < N1 + N2) {
    int i2 = idx - N1;
    int u = i2 / XD, d = i2 % XD;               // wyT[u*257+d] = Wy[d*128+u]
    wyT[i2] = Wy[d * HID + u];
  }
}

// ---------- kernel 2: px[t][b][j] = b_ih+b_hh + sum_d x[b][d][t]*Wih_gx[j][d] (bf16 out) ----------
__global__ __launch_bounds__(256) void k_proj(
    const float* __restrict__ x, const float* __restrict__ wT,
    const float* __restrict__ bih, const float* __restrict__ bhh,
    uint16_t* __restrict__ px) {
  __shared__ uint16_t xs[XD * 66];
  int tid = threadIdx.x;
  int t0 = blockIdx.x * 64, b = blockIdx.y;
  int lane = tid & 63;
  {
    int t = tid & 63, d0 = tid >> 6;
    for (int d = d0; d < XD; d += 4)
      xs[d * 66 + t] = f2bf(x[((size_t)b * XD + d) * T_SEQ + t0 + t]);
  }
  __syncthreads();
  int w = __builtin_amdgcn_readfirstlane(tid >> 6);
  for (int p = 0; p < 8; ++p) {
    int j0 = w * 128 + p * 16;
    float acc[16];
#pragma unroll
    for (int i = 0; i < 16; ++i) acc[i] = bih[j0 + i] + bhh[j0 + i];
    for (int d = 0; d < XD; ++d) {
      float xv = bf2f(xs[d * 66 + lane]);
      const float* wrow = wT + (size_t)d * G4 + j0;
#pragma unroll
      for (int i = 0; i < 16; ++i) acc[i] = fmaf(wrow[i], xv, acc[i]);
    }
    size_t base = ((size_t)(t0 + lane) * BATCH + b) * G4 + j0;
    uint32_t pk[8];
#pragma unroll
    for (int i = 0; i < 8; ++i)
      pk[i] = (uint32_t)f2bf(acc[2 * i]) | ((uint32_t)f2bf(acc[2 * i + 1]) << 16);
    uint4* dst = (uint4*)(px + base);
    dst[0] = make_uint4(pk[0], pk[1], pk[2], pk[3]);
    dst[1] = make_uint4(pk[4], pk[5], pk[6], pk[7]);
  }
}

// ---------- kernel 3: backward LSTM g_x — quad layout, 1 barrier/step ----------
__global__ __launch_bounds__(512, 2) void k_lstm_gx(
    const uint16_t* __restrict__ px, const float* __restrict__ Whh,
    uint16_t* __restrict__ gx) {
  __shared__ __align__(16) float hl[2][HID];
  int tid = threadIdx.x, b = blockIdx.x;
  int u = tid >> 2, g = tid & 3;
  int j = g * HID + u;                  // gate row this thread owns
  float wr[HID];
#pragma unroll
  for (int k = 0; k < HID; ++k) wr[k] = Whh[(size_t)j * HID + k];
  if (tid < HID) hl[0][tid] = 0.0f;
  float c = 0.0f;
  int cur = 0;
  int ql = (tid & 63) & ~3;
  bool isg = (g == 2);
  uint16_t pcur = px[((size_t)(T_SEQ - 1) * BATCH + b) * G4 + j];
  __syncthreads();
  for (int t = T_SEQ - 1; t >= 0; --t) {
    int tn = t > 0 ? t - 1 : 0;
    uint16_t pnext = px[((size_t)tn * BATCH + b) * G4 + j];
    float pre = bf2f(pcur);
    const float4* h4 = (const float4*)hl[cur];
#pragma unroll
    for (int k4 = 0; k4 < HID / 4; ++k4) {
      float4 h = h4[k4];
      pre = fmaf(wr[4 * k4 + 0], h.x, pre);
      pre = fmaf(wr[4 * k4 + 1], h.y, pre);
      pre = fmaf(wr[4 * k4 + 2], h.z, pre);
      pre = fmaf(wr[4 * k4 + 3], h.w, pre);
    }
    float act = gate_act(pre, isg);
    float af = __shfl(act, ql + 1);
    float ag = __shfl(act, ql + 2);
    float ao = __shfl(act, ql + 3);
    if (g == 0) {
      c = af * c + act * ag;
      float h = ao * tanhfast(c);
      hl[cur ^ 1][u] = h;
      gx[((size_t)t * BATCH + b) * HID + u] = f2bf(h);
    }
    cur ^= 1;
    pcur = pnext;
    __syncthreads();
  }
}

// ---------- kernel 4: fused inference — quad layout, 3 barriers/step ----------
__global__ __launch_bounds__(512, 2) void k_inf(
    const uint16_t* __restrict__ gx, const float* __restrict__ eps,
    const float* __restrict__ Wih_gz, const float* __restrict__ Whh_gz,
    const float* __restrict__ bih_gz, const float* __restrict__ bhh_gz,
    const float* __restrict__ W0, const float* __restrict__ b0,
    const float* __restrict__ Wm, const float* __restrict__ bm,
    const float* __restrict__ Wv, const float* __restrict__ bv,
    float* __restrict__ zbuf, float* __restrict__ out_mean,
    float* __restrict__ out_logvar, float* __restrict__ out_z) {
  __shared__ float wgzT2[ZD * 512];                 // column-permuted by tid: [k][tid]
  __shared__ __align__(16) float gxl[HID];
  __shared__ __align__(16) float gzl[2][HID];
  __shared__ __align__(16) float hvec[HID];
  __shared__ __align__(16) float zl[ZD];
  int tid = threadIdx.x, b = blockIdx.x;
  int u = tid >> 2, g = tid & 3;
  int j = g * HID + u;
  // z-projection weights, stride-1 per tid (conflict-free reads)
#pragma unroll
  for (int k = 0; k < ZD; ++k) wgzT2[k * 512 + tid] = Wih_gz[(size_t)j * ZD + k];
  float wzr[HID];
#pragma unroll
  for (int k = 0; k < HID; ++k) wzr[k] = Whh_gz[(size_t)j * HID + k];
  float bzr = bih_gz[j] + bhh_gz[j];
  float w0r[64];
#pragma unroll
  for (int i = 0; i < 64; ++i) w0r[i] = W0[(size_t)u * 256 + g * 64 + i];
  float b0r = b0[u];
  // stage-C mapping: 32 lanes per output o; lanes 0-15 mean, 16-31 logvar
  int o = tid >> 5, lo = tid & 31;
  float wmr[8];
  {
    const float* Wsel = (lo < 16) ? (Wm + (size_t)o * HID + lo * 8)
                                  : (Wv + (size_t)o * HID + (lo - 16) * 8);
#pragma unroll
    for (int i = 0; i < 8; ++i) wmr[i] = Wsel[i];
  }
  float bmr = bm[o], bvr = bv[o];
  float czr = 0.0f;
  int cur = 0;
  int ql = (tid & 63) & ~3;
  bool isg = (g == 2);
  if (tid < HID) {
    gzl[0][tid] = 0.0f;
    gxl[tid] = bf2f(gx[(size_t)b * HID + tid]);
  }
  float epcur = (lo == 0) ? eps[(size_t)b * ZD + o] : 0.0f;
  __syncthreads();
  for (int t = 0; t < T_SEQ; ++t) {
    int tn = (t < T_SEQ - 1) ? t + 1 : t;
    float gxnext = (tid < HID) ? bf2f(gx[((size_t)tn * BATCH + b) * HID + tid]) : 0.0f;
    float epnext = (lo == 0) ? eps[((size_t)tn * BATCH + b) * ZD + o] : 0.0f;
    // ---- stage B: h = tanh([gx, gz] @ W0.T + b0), quad shuffle-reduce ----
    {
      const float4* src = (const float4*)((g < 2) ? (gxl + g * 64) : (gzl[cur] + (g - 2) * 64));
      float p = 0.0f;
#pragma unroll
      for (int i4 = 0; i4 < 16; ++i4) {
        float4 v = src[i4];
        p = fmaf(w0r[4 * i4 + 0], v.x, p);
        p = fmaf(w0r[4 * i4 + 1], v.y, p);
        p = fmaf(w0r[4 * i4 + 2], v.z, p);
        p = fmaf(w0r[4 * i4 + 3], v.w, p);
      }
      p += __shfl_xor(p, 1);
      p += __shfl_xor(p, 2);
      if (g == 0) hvec[u] = tanhfast(p + b0r);
    }
    __syncthreads();  // b1
    // ---- stage C: mean/logvar/z fused, weights in VGPRs ----
    {
      int hbase = (lo & 15) * 8;
      const float4* hh = (const float4*)(hvec + hbase);
      float4 h0 = hh[0], h1 = hh[1];
      float p = wmr[0] * h0.x + wmr[1] * h0.y + wmr[2] * h0.z + wmr[3] * h0.w +
                wmr[4] * h1.x + wmr[5] * h1.y + wmr[6] * h1.z + wmr[7] * h1.w;
      p += __shfl_xor(p, 1);
      p += __shfl_xor(p, 2);
      p += __shfl_xor(p, 4);
      p += __shfl_xor(p, 8);
      float other = __shfl_xor(p, 16);   // lanes 0-15 get logvar sum, 16-31 get mean sum
      if (lo == 0) {
        float mean = p + bmr;
        float lv = other + bvr;
        float zv = epcur * __expf(0.5f * lv) + mean;
        zl[o] = zv;
        out_mean[((size_t)b * ZD + o) * T_SEQ + t] = mean;
        out_logvar[((size_t)b * ZD + o) * T_SEQ + t] = lv;
        out_z[((size_t)b * ZD + o) * T_SEQ + t] = zv;
        zbuf[((size_t)t * BATCH + b) * ZD + o] = zv;
      }
    }
    __syncthreads();  // b2
    // ---- stage A: g_z LSTM cell gates + in-quad update ----
    {
      float pre = bzr;
#pragma unroll
      for (int k = 0; k < ZD; ++k) pre = fmaf(zl[k], wgzT2[k * 512 + tid], pre);
      const float4* g4 = (const float4*)gzl[cur];
#pragma unroll
      for (int k4 = 0; k4 < HID / 4; ++k4) {
        float4 hv = g4[k4];
        pre = fmaf(wzr[4 * k4 + 0], hv.x, pre);
        pre = fmaf(wzr[4 * k4 + 1], hv.y, pre);
        pre = fmaf(wzr[4 * k4 + 2], hv.z, pre);
        pre = fmaf(wzr[4 * k4 + 3], hv.w, pre);
      }
      float act = gate_act(pre, isg);
      float af = __shfl(act, ql + 1);
      float ag = __shfl(act, ql + 2);
      float ao = __shfl(act, ql + 3);
      if (g == 0) {
        czr = af * czr + act * ag;
        gzl[cur ^ 1][u] = ao * tanhfast(czr);
      }
      if (tid < HID) gxl[tid] = gxnext;
    }
    epcur = epnext;
    cur ^= 1;
    __syncthreads();  // b3
  }
}

// ---------- kernel 5: decoder LSTM — quad layout, 1 barrier/step ----------
__global__ __launch_bounds__(512, 2) void k_dec(
    const float* __restrict__ zbuf, const float* __restrict__ Wih_h,
    const float* __restrict__ Whh_h, const float* __restrict__ bih,
    const float* __restrict__ bhh, uint16_t* __restrict__ hdec) {
  __shared__ float wihT2[ZD * 512];                 // column-permuted by tid
  __shared__ __align__(16) float hl[2][HID];
  __shared__ float zls[2][ZD];
  int tid = threadIdx.x, b = blockIdx.x;
  int u = tid >> 2, g = tid & 3;
  int j = g * HID + u;
#pragma unroll
  for (int k = 0; k < ZD; ++k) wihT2[k * 512 + tid] = Wih_h[(size_t)j * ZD + k];
  float wr[HID];
#pragma unroll
  for (int k = 0; k < HID; ++k) wr[k] = Whh_h[(size_t)j * HID + k];
  float bz = bih[j] + bhh[j];
  if (tid < HID) hl[0][tid] = 0.0f;
  if (tid < ZD) zls[0][tid] = zbuf[(size_t)b * ZD + tid];
  float c = 0.0f;
  int cur = 0;
  int ql = (tid & 63) & ~3;
  bool isg = (g == 2);
  __syncthreads();
  for (int t = 0; t < T_SEQ; ++t) {
    int tn = (t < T_SEQ - 1) ? t + 1 : t;
    float znext = (tid < ZD) ? zbuf[((size_t)tn * BATCH + b) * ZD + tid] : 0.0f;
    float pre = bz;
#pragma unroll
    for (int k = 0; k < ZD; ++k) pre = fmaf(zls[cur][k], wihT2[k * 512 + tid], pre);
    const float4* h4 = (const float4*)hl[cur];
#pragma unroll
    for (int k4 = 0; k4 < HID / 4; ++k4) {
      float4 h = h4[k4];
      pre = fmaf(wr[4 * k4 + 0], h.x, pre);
      pre = fmaf(wr[4 * k4 + 1], h.y, pre);
      pre = fmaf(wr[4 * k4 + 2], h.z, pre);
      pre = fmaf(wr[4 * k4 + 3], h.w, pre);
    }
    float act = gate_act(pre, isg);
    float af = __shfl(act, ql + 1);
    float ag = __shfl(act, ql + 2);
    float ao = __shfl(act, ql + 3);
    if (g == 0) {
      c = af * c + act * ag;
      float h = ao * tanhfast(c);
      hl[cur ^ 1][u] = h;
      hdec[((size_t)t * BATCH + b) * HID + u] = f2bf(h);
    }
    if (tid < ZD) zls[cur ^ 1][tid] = znext;
    cur ^= 1;
    __syncthreads();
  }
}

// ---------- kernel 6: y = exp(hdec @ Wy.T + by), output (B, 257, T) ----------
__global__ __launch_bounds__(256) void k_y(
    const uint16_t* __restrict__ hdec, const float* __restrict__ wyT,
    const float* __restrict__ by, float* __restrict__ out_y) {
  __shared__ __align__(16) float hl[HID * 65];
  int tid = threadIdx.x;
  int t0 = blockIdx.x * 64, b = blockIdx.y;
  {
    int uu = tid & 127, tg = tid >> 7;
    for (int tt = tg; tt < 64; tt += 2)
      hl[uu * 65 + tt] = bf2f(hdec[((size_t)(t0 + tt) * BATCH + b) * HID + uu]);
  }
  __syncthreads();
  int w = __builtin_amdgcn_readfirstlane(tid >> 6);
  int lane = tid & 63;
  for (int p = 0; p < 4; ++p) {
    int d0 = w * 16 + p * 64;
    float acc[16];
#pragma unroll
    for (int i = 0; i < 16; ++i) acc[i] = by[d0 + i];
    for (int uu = 0; uu < HID; ++uu) {
      float hv = hl[uu * 65 + lane];
      const float* wrow = wyT + (size_t)uu * XD + d0;
#pragma unroll
      for (int i = 0; i < 16; ++i) acc[i] = fmaf(wrow[i], hv, acc[i]);
    }
#pragma unroll
    for (int i = 0; i < 16; ++i)
      out_y[((size_t)b * XD + d0 + i) * T_SEQ + t0 + lane] = __expf(acc[i]);
  }
  if (w == 0) {  // d = 256 tail
    float acc = by[256];
    for (int uu = 0; uu < HID; ++uu)
      acc = fmaf(wyT[(size_t)uu * XD + 256], hl[uu * 65 + lane], acc);
    out_y[((size_t)b * XD + 256) * T_SEQ + t0 + lane] = __expf(acc);
  }
}

extern "C" void kernel_launch(void* const* d_in, const int* in_sizes, int n_in,
                              void* d_out, int out_size, void* d_ws, size_t ws_size,
                              hipStream_t stream) {
  const float* x      = (const float*)d_in[0];
  const float* eps    = (const float*)d_in[1];
  const float* Wih_gx = (const float*)d_in[2];
  const float* Whh_gx = (const float*)d_in[3];
  const float* bih_gx = (const float*)d_in[4];
  const float* bhh_gx = (const float*)d_in[5];
  const float* Wih_gz = (const float*)d_in[6];
  const float* Whh_gz = (const float*)d_in[7];
  const float* bih_gz = (const float*)d_in[8];
  const float* bhh_gz = (const float*)d_in[9];
  const float* W0     = (const float*)d_in[10];
  const float* b0     = (const float*)d_in[11];
  const float* Wm     = (const float*)d_in[12];
  const float* bm     = (const float*)d_in[13];
  const float* Wv     = (const float*)d_in[14];
  const float* bv     = (const float*)d_in[15];
  const float* Wih_h  = (const float*)d_in[16];
  const float* Whh_h  = (const float*)d_in[17];
  const float* bih_h  = (const float*)d_in[18];
  const float* bhh_h  = (const float*)d_in[19];
  const float* Wy     = (const float*)d_in[20];
  const float* by     = (const float*)d_in[21];

  char* ws = (char*)d_ws;
  float*    wT   = (float*)(ws + 0);                       // 257*512 f32   = 526,336 B
  float*    wyT  = (float*)(ws + 526336);                  // 128*257 f32   = 131,584 B
  uint16_t* px   = (uint16_t*)(ws + (1u << 20));           // bf16 T*B*512  = 134,217,728 B
  uint16_t* gx   = (uint16_t*)(ws + 135266304);            // bf16 T*B*128  =  33,554,432 B
  float*    zbuf = (float*)(ws + 168820736);               // f32  T*B*16   =   8,388,608 B
  uint16_t* hdec = (uint16_t*)(ws + 177209344);            // bf16 T*B*128  =  33,554,432 B

  float* out_y      = (float*)d_out;                         // (B,257,T)
  float* out_mean   = out_y + (size_t)BATCH * XD * T_SEQ;    // (B,16,T)
  float* out_logvar = out_mean + (size_t)BATCH * ZD * T_SEQ;
  float* out_z      = out_logvar + (size_t)BATCH * ZD * T_SEQ;

  k_prep<<<dim3(643), dim3(256), 0, stream>>>(Wih_gx, Wy, wT, wyT);
  k_proj<<<dim3(8, 256), dim3(256), 0, stream>>>(x, wT, bih_gx, bhh_gx, px);
  k_lstm_gx<<<dim3(256), dim3(512), 0, stream>>>(px, Whh_gx, gx);
  k_inf<<<dim3(256), dim3(512), 0, stream>>>(gx, eps, Wih_gz, Whh_gz, bih_gz, bhh_gz,
                                             W0, b0, Wm, bm, Wv, bv,
                                             zbuf, out_mean, out_logvar, out_z);
  k_dec<<<dim3(256), dim3(512), 0, stream>>>(zbuf, Wih_h, Whh_h, bih_h, bhh_h, hdec);
  k_y<<<dim3(8, 256), dim3(256), 0, stream>>>(hdec, wyT, by, out_y);
}